// Round 7
// baseline (299.751 us; speedup 1.0000x reference)
//
#include <hip/hip_runtime.h>
#include <hip/hip_bf16.h>
#include <hip/hip_cooperative_groups.h>

// ---------------- problem constants ----------------
#define B_    4
#define TQ_   1024
#define TKV_  1024
#define NPR_  5
#define H_    16
#define D_    64
#define IN_   1024
#define OUT_  1024
#define R_    64
#define KV_   1029            // NPR + TKV
#define KVP_  1088            // KV padded to 17*64
#define M1_   4116            // B*KV
#define M1P_  4160            // padded to 65*64
#define MQ_   4096            // B*TQ
#define NKT_  17              // KVP_/64
#define NQT_  16
#define MR_   (M1P_ * R_)     // 266240, one partial-chunk slice
#define LOG2E_ 1.4426950408889634f
#define SQ_SCALE_ (0.125f * 1.4426950408889634f)

typedef __attribute__((ext_vector_type(8))) short short8;
typedef __attribute__((ext_vector_type(4))) float f32x4;
typedef __attribute__((ext_vector_type(4))) unsigned uint4v;
typedef __attribute__((ext_vector_type(2))) unsigned uint2v;

#define MFMA(a, b, c) __builtin_amdgcn_mfma_f32_16x16x32_bf16(a, b, c, 0, 0, 0)

#define AS1 __attribute__((address_space(1)))
#define AS3 __attribute__((address_space(3)))
#define GLDS(g, l) __builtin_amdgcn_global_load_lds((const AS1 void*)(g), (AS3 void*)(l), 16, 0, 0)

static __device__ __forceinline__ short f2bf(float f) {
  unsigned u = __builtin_bit_cast(unsigned, f);
  u += 0x7fffu + ((u >> 16) & 1u);
  return (short)(u >> 16);
}
static __device__ __forceinline__ float bf2f(unsigned short u) {
  return __builtin_bit_cast(float, (unsigned)u << 16);
}
static __device__ __forceinline__ short8 zero8() {
  short8 z = {0, 0, 0, 0, 0, 0, 0, 0};
  return z;
}
static __device__ __forceinline__ unsigned cvtpk(float lo, float hi) {
  unsigned r;
  asm("v_cvt_pk_bf16_f32 %0, %1, %2" : "=v"(r) : "v"(lo), "v"(hi));
  return r;
}
static __device__ __forceinline__ float vexp2(float x) {   // raw v_exp (2^x)
  float r;
  asm("v_exp_f32 %0, %1" : "=v"(r) : "v"(x));
  return r;
}
static __device__ __forceinline__ void pl32(unsigned &a, unsigned &b) {
  asm("v_permlane32_swap_b32 %0, %1" : "+v"(a), "+v"(b));
}
static __device__ __forceinline__ void pl16(unsigned &a, unsigned &b) {
  asm("v_permlane16_swap_b32 %0, %1" : "+v"(a), "+v"(b));
}
static __device__ __forceinline__ float redsum4(float x) {
  unsigned a = __builtin_bit_cast(unsigned, x), b = a;
  pl16(a, b);
  x = __builtin_bit_cast(float, a) + __builtin_bit_cast(float, b);
  a = b = __builtin_bit_cast(unsigned, x);
  pl32(a, b);
  return __builtin_bit_cast(float, a) + __builtin_bit_cast(float, b);
}
// C-layout f32 s[4] -> bf16 B-fragments (validated R1..R6)
static __device__ __forceinline__ void cd2bfrag(const f32x4 (&s)[4], short8 &p0, short8 &p1) {
  unsigned u00 = cvtpk(s[0][0], s[0][1]), u01 = cvtpk(s[0][2], s[0][3]);
  unsigned u10 = cvtpk(s[1][0], s[1][1]), u11 = cvtpk(s[1][2], s[1][3]);
  unsigned u20 = cvtpk(s[2][0], s[2][1]), u21 = cvtpk(s[2][2], s[2][3]);
  unsigned u30 = cvtpk(s[3][0], s[3][1]), u31 = cvtpk(s[3][2], s[3][3]);
  pl32(u00, u10); pl32(u01, u11); pl32(u20, u30); pl32(u21, u31);
  pl16(u00, u10); pl16(u01, u11); pl16(u20, u30); pl16(u21, u31);
  uint4v w0 = {u00, u01, u10, u11};
  uint4v w1 = {u20, u21, u30, u31};
  p0 = __builtin_bit_cast(short8, w0);
  p1 = __builtin_bit_cast(short8, w1);
}
// sum 4 bf16 partial chunks (stride MR_) -> bf16 fragment
static __device__ __forceinline__ short8 sum4pack(const unsigned short* p) {
  f32x4 lo = {0, 0, 0, 0}, hi = {0, 0, 0, 0};
#pragma unroll
  for (int c = 0; c < 4; ++c) {
    short8 v = *(const short8*)(p + (size_t)c * MR_);
#pragma unroll
    for (int j = 0; j < 4; ++j) {
      lo[j] += bf2f((unsigned short)v[j]);
      hi[j] += bf2f((unsigned short)v[j + 4]);
    }
  }
  uint4v u = {cvtpk(lo[0], lo[1]), cvtpk(lo[2], lo[3]),
              cvtpk(hi[0], hi[1]), cvtpk(hi[2], hi[3])};
  return __builtin_bit_cast(short8, u);
}

// ================= kernel 1: cooperative fused projection pipeline =================
// P0: weight transpose + mask tile scan | sync | P1: stage1 (K-split x4) | sync | P2: stage2
__global__ __launch_bounds__(256, 4) void proj(
    const float* __restrict__ prompt, const float* __restrict__ kv_query,
    const float* __restrict__ pe,
    const int* __restrict__ indices_a, const int* __restrict__ indices_b,
    const int* __restrict__ task_idx,
    const float* __restrict__ kw1, const float* __restrict__ vw1,
    const float* __restrict__ kpw1, const float* __restrict__ qpw1,
    const float* __restrict__ kw2, const float* __restrict__ vw2,
    const float* __restrict__ kpw2, const float* __restrict__ qpw2,
    const float* __restrict__ mask,
    short* __restrict__ w1t, short* __restrict__ w2t,
    unsigned short* __restrict__ part,
    short* __restrict__ kbf, short* __restrict__ vtb, short* __restrict__ tqs,
    int* __restrict__ mflags) {
  cooperative_groups::grid_group gg = cooperative_groups::this_grid();
  int bid = blockIdx.x;
  int lane = threadIdx.x & 63, wave = threadIdx.x >> 6;
  int lrow = lane & 15, lg = lane >> 4;
  const f32x4 fz = {0, 0, 0, 0};
  __shared__ int snz[4];

  // ---------------- P0: weights + mask scan ----------------
  if (bid < 64) {
    int tid = bid * 256 + threadIdx.x;
    const float* w1s[4] = {kw1, vw1, kpw1, qpw1};
    const float* w2s[4] = {kw2, vw2, kpw2, qpw2};
    for (int i = tid; i < 4 * R_ * IN_; i += 64 * 256) {
      int m = i >> 16, p = i & 65535, r = p >> 10, k = p & 1023;
      w1t[i] = f2bf(w1s[m][k * R_ + r]);
    }
    for (int i = tid; i < 4 * OUT_ * R_; i += 64 * 256) {
      int m = i >> 16, p = i & 65535, o = p >> 6, r = p & 63;
      w2t[i] = f2bf(w2s[m][r * OUT_ + o]);
    }
  } else if (bid < 336) {
    int t = bid - 64;                 // 0..271 : tile (qt, kt)
    int qt = t / NKT_, kt = t % NKT_;
    int nz = 0;
    for (int it = 0; it < 16; ++it) {
      int e = it * 256 + threadIdx.x;
      int rr = e >> 6, cc = e & 63;
      int kv = kt * 64 + cc;
      if (kv < KV_) {
        float v = mask[(size_t)(qt * 64 + rr) * KV_ + kv];
        nz |= (v != 0.0f);
      }
    }
    unsigned long long bv = __ballot(nz);
    if ((threadIdx.x & 63) == 0) snz[threadIdx.x >> 6] = (bv != 0ULL);
    __syncthreads();
    if (threadIdx.x == 0) mflags[t] = snz[0] | snz[1] | snz[2] | snz[3];
  }

  gg.sync();

  // ---------------- P1: stage1, K-split x4, C^T packed stores ----------------
  if (bid < 780) {
    int which = bid / 260, rem = bid - which * 260;
    int chunk = rem / 65, mt = rem - chunk * 65;
    if (!(which == 2 && mt >= 64)) {
      int mbase = mt * 64;
      int row = mbase + wave * 16 + lrow;
      const float* asrc = nullptr;
      if (which == 0) {
        int r = min(row, M1_ - 1);
        int b = r / KV_, t = r - b * KV_;
        asrc = (t < NPR_) ? prompt + (size_t)(task_idx[b] * NPR_ + t) * IN_
                          : kv_query + (size_t)(b * TKV_ + t - NPR_) * IN_;
      } else if (which == 1) {
        int r = min(row, M1_ - 1);
        int b = r / KV_, t = r - b * KV_;
        if (t >= NPR_) asrc = pe + (size_t)indices_b[b * TKV_ + t - NPR_] * OUT_;
      } else {
        int r = min(row, MQ_ - 1);
        asrc = pe + (size_t)indices_a[r] * OUT_;
      }
      const short* bt0 = w1t + (size_t)((which == 0) ? 0 : (which == 1) ? 2 : 3) * (R_ * IN_);
      const short* bt1 = w1t + (size_t)1 * (R_ * IN_);
      int k0base = chunk * 256;

      f32x4 acc0[4], acc1[4];
#pragma unroll
      for (int f = 0; f < 4; ++f) { acc0[f] = fz; acc1[f] = fz; }

#pragma unroll 2
      for (int ks = 0; ks < 8; ++ks) {
        int kc = k0base + ks * 32 + lg * 8;
        short8 bdat;
        if (asrc) {
          f32x4 a0 = *(const f32x4*)(asrc + kc);
          f32x4 a1 = *(const f32x4*)(asrc + kc + 4);
          uint4v au = {cvtpk(a0[0], a0[1]), cvtpk(a0[2], a0[3]),
                       cvtpk(a1[0], a1[1]), cvtpk(a1[2], a1[3])};
          bdat = __builtin_bit_cast(short8, au);
        } else {
          bdat = zero8();
        }
#pragma unroll
        for (int f = 0; f < 4; ++f) {
          short8 w0 = *(const short8*)(bt0 + (size_t)(f * 16 + lrow) * IN_ + kc);
          acc0[f] = MFMA(w0, bdat, acc0[f]);      // C^T: lane = m-row, acc idx = R
          if (which == 0) {
            short8 w1f = *(const short8*)(bt1 + (size_t)(f * 16 + lrow) * IN_ + kc);
            acc1[f] = MFMA(w1f, bdat, acc1[f]);
          }
        }
      }
      int o0 = (which == 0) ? 0 : (which == 1) ? 2 : 3;
      size_t mrow = (size_t)(mbase + wave * 16 + lrow) * R_;
      unsigned short* p0 = part + (size_t)(o0 * 4 + chunk) * MR_ + mrow;
#pragma unroll
      for (int f = 0; f < 4; ++f) {
        uint2v w = {cvtpk(acc0[f][0], acc0[f][1]), cvtpk(acc0[f][2], acc0[f][3])};
        *(uint2v*)(p0 + f * 16 + lg * 4) = w;
      }
      if (which == 0) {
        unsigned short* p1 = part + (size_t)(4 + chunk) * MR_ + mrow;
#pragma unroll
        for (int f = 0; f < 4; ++f) {
          uint2v w = {cvtpk(acc1[f][0], acc1[f][1]), cvtpk(acc1[f][2], acc1[f][3])};
          *(uint2v*)(p1 + f * 16 + lg * 4) = w;
        }
      }
    }
  }

  gg.sync();

  // ---------------- P2: stage2, fused 4-chunk reduce + proj -> swizzled tiles ----------------
  int L = bid;
  if (L < 272) {                       // ---- K: kbf = tk@k_w2 + tkp@kp_w2 ----
    int virt = (L & 7) * 34 + (L >> 3);      // nh-siblings share an XCD
    int mt = virt >> 2, nh = virt & 3;
    int orow = mt * 64 + wave * 16 + lrow;
    int ob = orow / KVP_, okv = orow - ob * KVP_;
    bool valid = (okv < KV_);
    int kt = okv >> 6, rin = okv & 63;
    int prow = ob * KV_ + min(okv, KV_ - 1);
    short8 b1[2], b2[2];
#pragma unroll
    for (int ks = 0; ks < 2; ++ks) {
      int kc = ks * 32 + lg * 8;
      b1[ks] = valid ? sum4pack(part + (size_t)prow * R_ + kc) : zero8();
      b2[ks] = valid ? sum4pack(part + (size_t)8 * MR_ + (size_t)prow * R_ + kc) : zero8();
    }
    const short* w2k  = w2t;
    const short* w2kp = w2t + (size_t)2 * (OUT_ * R_);
    int sw = (rin & 7) << 3;
#pragma unroll
    for (int i = 0; i < 4; ++i) {
      int nbase = (nh * 4 + i) * 64;
      int h = nbase >> 6;
      f32x4 acc[4];
#pragma unroll
      for (int f = 0; f < 4; ++f) acc[f] = fz;
#pragma unroll
      for (int ks = 0; ks < 2; ++ks) {
        int kc = ks * 32 + lg * 8;
#pragma unroll
        for (int f = 0; f < 4; ++f) {
          short8 aK  = *(const short8*)(w2k  + (size_t)(nbase + f * 16 + lrow) * R_ + kc);
          short8 aKP = *(const short8*)(w2kp + (size_t)(nbase + f * 16 + lrow) * R_ + kc);
          acc[f] = MFMA(aK,  b1[ks], acc[f]);
          acc[f] = MFMA(aKP, b2[ks], acc[f]);
        }
      }
      size_t tb = ((size_t)((ob * H_ + h) * NKT_ + kt) << 12);
#pragma unroll
      for (int f = 0; f < 4; ++f) {
        float v0 = valid ? acc[f][0] : 0.f, v1 = valid ? acc[f][1] : 0.f;
        float v2 = valid ? acc[f][2] : 0.f, v3 = valid ? acc[f][3] : 0.f;
        uint2v w = {cvtpk(v0, v1), cvtpk(v2, v3)};
        int d0 = f * 16 + lg * 4;
        *(uint2v*)(kbf + tb + rin * 64 + (d0 ^ sw)) = w;
      }
    }
  } else if (L < 544) {                // ---- V: vtb = (tv @ v_w2)^T ----
    int Lm = L - 272;
    int virt = (Lm & 7) * 34 + (Lm >> 3);
    int cb = virt >> 2, oh = virt & 3;
    short8 afr[8];
#pragma unroll
    for (int f = 0; f < 4; ++f)
#pragma unroll
      for (int ks = 0; ks < 2; ++ks) {
        int crow = cb * 64 + f * 16 + lrow;
        int bb = crow / KVP_, kvr = crow - bb * KVP_;
        afr[f * 2 + ks] = (kvr < KV_)
            ? sum4pack(part + (size_t)4 * MR_ + (size_t)(bb * KV_ + kvr) * R_ + ks * 32 + lg * 8)
            : zero8();
      }
    int bb = (cb * 64) / KVP_;
    int kvbase = cb * 64 - bb * KVP_;        // 64-aligned
    int kt = kvbase >> 6;
    const short* w2v = w2t + (size_t)1 * (OUT_ * R_);
#pragma unroll
    for (int i = 0; i < 4; ++i) {
      int obase = (oh * 4 + i) * 64;
      int o = obase + wave * 16 + lrow;
      int h = o >> 6, d = o & 63;
      f32x4 acc[4];
#pragma unroll
      for (int f = 0; f < 4; ++f) acc[f] = fz;
#pragma unroll
      for (int ks = 0; ks < 2; ++ks) {
        short8 bw = *(const short8*)(w2v + (size_t)o * R_ + ks * 32 + lg * 8);
#pragma unroll
        for (int f = 0; f < 4; ++f) acc[f] = MFMA(afr[f * 2 + ks], bw, acc[f]);
      }
      int sw = (d & 7) << 3;
      size_t tb = ((size_t)((bb * H_ + h) * NKT_ + kt) << 12);
#pragma unroll
      for (int f = 0; f < 4; ++f) {
        int kvin0 = f * 16 + lg * 4;
        float v0 = (kvbase + kvin0 + 0 < KV_) ? acc[f][0] : 0.f;
        float v1 = (kvbase + kvin0 + 1 < KV_) ? acc[f][1] : 0.f;
        float v2 = (kvbase + kvin0 + 2 < KV_) ? acc[f][2] : 0.f;
        float v3 = (kvbase + kvin0 + 3 < KV_) ? acc[f][3] : 0.f;
        uint2v w = {cvtpk(v0, v1), cvtpk(v2, v3)};
        *(uint2v*)(vtb + tb + d * 64 + (kvin0 ^ sw)) = w;
      }
    }
  } else if (L < 560) {                // ---- tq partial sum -> tqs ----
    int j = L - 544;                   // 0..15
#pragma unroll
    for (int it = 0; it < 8; ++it) {
      int idx = j * 16384 + it * 2048 + threadIdx.x * 8;
      short8 v = sum4pack(part + (size_t)12 * MR_ + idx);
      *(short8*)(tqs + idx) = v;
    }
  }
}

// ================= kernel 2: flash attention, 3-buffer 1-barrier pipeline =================
__global__ __launch_bounds__(256, 3) void attn(
    const short* __restrict__ tqs, const short* __restrict__ w2t,
    const float* __restrict__ qin,
    const short* __restrict__ kbf, const short* __restrict__ vtb,
    const float* __restrict__ mask, const int* __restrict__ mflags,
    const float* __restrict__ gates, const float* __restrict__ attn_in,
    float* __restrict__ out) {
  int bid = blockIdx.x;
  int xcd = bid & 7, wg = bid >> 3;
  int qt = wg & 15, g = wg >> 4;
  int grp = xcd * 8 + g;                 // all 16 qt of a (b,h) share one XCD
  int h = grp & 15, b = grp >> 4;

  int lane = threadIdx.x & 63, wave = threadIdx.x >> 6;
  int lrow = lane & 15, lg = lane >> 4;
  int qbase = qt * 64 + wave * 16;

  __shared__ __align__(16) short kvls[3][2][4096];   // [buf][K/V][64x64 swizzled]

  const short* ktile = kbf + ((size_t)grp * NKT_ << 12);
  const short* vtile = vtb + ((size_t)grp * NKT_ << 12);
  const short* kg = ktile + wave * 512 + lane * 8;
  const short* vg = vtile + wave * 512 + lane * 8;

  int sw = (lrow & 7) << 3;
  int offA = (lg * 8) ^ sw;
  int offB = (32 + lg * 8) ^ sw;
  const short* p0A = &kvls[0][0][lrow * 64 + offA];
  const short* p0B = &kvls[0][0][lrow * 64 + offB];
  const short* p1A = &kvls[1][0][lrow * 64 + offA];
  const short* p1B = &kvls[1][0][lrow * 64 + offB];
  const short* p2A = &kvls[2][0][lrow * 64 + offA];
  const short* p2B = &kvls[2][0][lrow * 64 + offB];
  const int* mfp = mflags + qt * NKT_;

  auto stage = [&](int t, int bsel) {
    const short* ks = kg + ((size_t)t << 12);
    const short* vs = vg + ((size_t)t << 12);
    GLDS(ks,        &kvls[bsel][0][wave * 512]);
    GLDS(ks + 2048, &kvls[bsel][0][wave * 512 + 2048]);
    GLDS(vs,        &kvls[bsel][1][wave * 512]);
    GLDS(vs + 2048, &kvls[bsel][1][wave * 512 + 2048]);
  };

  stage(0, 0);
  stage(1, 1);

  // mask-tile flag bitmask (wave-uniform -> scalar branches in the loop)
  int fl = 0;
#pragma unroll
  for (int t = 0; t < NKT_; ++t) fl |= (mfp[t] ? 1 : 0) << t;
  fl = __builtin_amdgcn_readfirstlane(fl);

  const f32x4 fz = {0, 0, 0, 0};
  short8 qa0, qa1;
  {
    const short* w2q = w2t + (size_t)3 * (OUT_ * R_);
    f32x4 qs[4];
#pragma unroll
    for (int f = 0; f < 4; ++f) qs[f] = fz;
#pragma unroll
    for (int ks = 0; ks < 2; ++ks) {
      short8 tqf = *(const short8*)(tqs + (size_t)(b * TQ_ + qbase + lrow) * R_ + ks * 32 + lg * 8);
#pragma unroll
      for (int f = 0; f < 4; ++f) {
        short8 wf = *(const short8*)(w2q + (size_t)(h * 64 + f * 16 + lrow) * R_ + ks * 32 + lg * 8);
        qs[f] = MFMA(wf, tqf, qs[f]);
      }
    }
    const float* qrow = qin + (size_t)(b * TQ_ + qbase + lrow) * OUT_ + h * 64;
#pragma unroll
    for (int f = 0; f < 4; ++f) {
      f32x4 qv = *(const f32x4*)(qrow + f * 16 + lg * 4);
#pragma unroll
      for (int r = 0; r < 4; ++r) qs[f][r] = (qs[f][r] + qv[r]) * SQ_SCALE_;
    }
    cd2bfrag(qs, qa0, qa1);
  }

  f32x4 oacc[4];
#pragma unroll
  for (int f = 0; f < 4; ++f) oacc[f] = fz;
  float plsum = 0.f;

  // mode: 0 = stage(t+2), 1 = no stage, 2 = last (vmcnt(0) + pad)
  auto tile = [&](int t, const short* pA, const short* pB, int sb, int mode) {
    if (mode == 2) asm volatile("s_waitcnt vmcnt(0)" ::: "memory");
    else           asm volatile("s_waitcnt vmcnt(4)" ::: "memory");   // tile t landed; t+1 in flight
    __builtin_amdgcn_sched_barrier(0);
    __builtin_amdgcn_s_barrier();     // all waves: t staged, and done reading buf[(t+2)%3]
    __builtin_amdgcn_sched_barrier(0);
    if (mode == 0) stage(t + 2, sb);

    f32x4 s[4];
#pragma unroll
    for (int f = 0; f < 4; ++f) {
      short8 kA = *(const short8*)(pA + f * 1024);
      short8 kB = *(const short8*)(pB + f * 1024);
      s[f] = MFMA(kA, qa0, fz);
      s[f] = MFMA(kB, qa1, s[f]);
    }
    short8 vfr[8];
#pragma unroll
    for (int f = 0; f < 4; ++f) {
      vfr[f * 2 + 0] = *(const short8*)(pA + 4096 + f * 1024);
      vfr[f * 2 + 1] = *(const short8*)(pB + 4096 + f * 1024);
    }
    if ((fl >> t) & 1) {                               // nonzero mask tile (rare)
      int kvb = t * 64;
      const float* mrp = mask + (size_t)(qbase + lrow) * KV_;
#pragma unroll
      for (int f = 0; f < 4; ++f)
#pragma unroll
        for (int r = 0; r < 4; ++r) {
          int kv = kvb + f * 16 + lg * 4 + r;
          if (kv < KV_) s[f][r] += mrp[kv] * LOG2E_;
        }
    }
    if (mode == 2) {                                   // pad kv >= KV_
#pragma unroll
      for (int f = 0; f < 4; ++f)
#pragma unroll
        for (int r = 0; r < 4; ++r) {
          int kv = t * 64 + f * 16 + lg * 4 + r;
          if (kv >= KV_) s[f][r] = -1e30f;
        }
    }
    // static softmax numerator: P = 2^S (S in log2 units, bounded by data)
#pragma unroll
    for (int f = 0; f < 4; ++f)
#pragma unroll
      for (int r = 0; r < 4; ++r) s[f][r] = vexp2(s[f][r]);
    f32x4 st = (s[0] + s[1]) + (s[2] + s[3]);
    plsum += (st[0] + st[1]) + (st[2] + st[3]);        // per-lane partial
    short8 pb0, pb1;
    cd2bfrag(s, pb0, pb1);
#pragma unroll
    for (int f = 0; f < 4; ++f) {
      oacc[f] = MFMA(vfr[f * 2 + 0], pb0, oacc[f]);
      oacc[f] = MFMA(vfr[f * 2 + 1], pb1, oacc[f]);
    }
  };

#pragma unroll 1
  for (int i = 0; i < 5; ++i) {                        // t = 0..14
    tile(3 * i + 0, p0A, p0B, 2, 0);
    tile(3 * i + 1, p1A, p1B, 0, 0);
    tile(3 * i + 2, p2A, p2B, 1, 0);
  }
  tile(15, p0A, p0B, 2, 1);
  tile(16, p1A, p1B, 0, 2);

  float lsum = redsum4(plsum);
  float sc = gates[0] / lsum;
  const float* ain = attn_in + (size_t)(b * TQ_ + qbase + lrow) * OUT_ + h * 64;
  float* op = out + (size_t)(b * TQ_ + qbase + lrow) * OUT_ + h * 64;
#pragma unroll
  for (int f = 0; f < 4; ++f) {
    f32x4 av = *(const f32x4*)(ain + f * 16 + lg * 4);
    f32x4 ov;
#pragma unroll
    for (int r = 0; r < 4; ++r) ov[r] = oacc[f][r] * sc + av[r];
    *(f32x4*)(op + f * 16 + lg * 4) = ov;
  }
}

// ---------------- launcher ----------------
extern "C" void kernel_launch(void* const* d_in, const int* in_sizes, int n_in,
                              void* d_out, int out_size, void* d_ws, size_t ws_size,
                              hipStream_t stream) {
  const float* pe          = (const float*)d_in[0];
  const float* attn_output = (const float*)d_in[1];
  const float* q           = (const float*)d_in[2];
  const float* kv_query    = (const float*)d_in[3];
  const float* attn_mask   = (const float*)d_in[4];
  const float* prompt      = (const float*)d_in[5];
  const float* gates       = (const float*)d_in[6];
  const float* k_w1        = (const float*)d_in[7];
  const float* k_w2        = (const float*)d_in[8];
  const float* v_w1        = (const float*)d_in[9];
  const float* v_w2        = (const float*)d_in[10];
  const float* kp_w1       = (const float*)d_in[11];
  const float* kp_w2       = (const float*)d_in[12];
  const float* qp_w1       = (const float*)d_in[13];
  const float* qp_w2       = (const float*)d_in[14];
  const int* indices_a     = (const int*)d_in[15];
  const int* indices_b     = (const int*)d_in[16];
  const int* task_idx      = (const int*)d_in[17];
  float* out = (float*)d_out;

  const size_t TILEB = (size_t)64 * NKT_ * 4096;      // elems per K or V buffer

  short* ws   = (short*)d_ws;
  short* w1t  = ws;                                   // 262144
  short* w2t  = w1t + 4 * 65536;                      // 262144
  unsigned short* part = (unsigned short*)(w2t + 4 * 65536);  // 16 * MR_
  short* tqs  = (short*)(part + (size_t)16 * MR_);    // 262144
  short* kbf  = tqs + (size_t)MQ_ * R_;               // 4456448
  short* vtb  = kbf + TILEB;                          // 4456448
  int* mflags = (int*)(vtb + TILEB);                  // 272 ints
  // total ≈ 27.8 MB

  void* args[] = {
      (void*)&prompt, (void*)&kv_query, (void*)&pe,
      (void*)&indices_a, (void*)&indices_b, (void*)&task_idx,
      (void*)&k_w1, (void*)&v_w1, (void*)&kp_w1, (void*)&qp_w1,
      (void*)&k_w2, (void*)&v_w2, (void*)&kp_w2, (void*)&qp_w2,
      (void*)&attn_mask,
      (void*)&w1t, (void*)&w2t, (void*)&part,
      (void*)&kbf, (void*)&vtb, (void*)&tqs, (void*)&mflags};
  hipLaunchCooperativeKernel(reinterpret_cast<void*>(proj), dim3(780), dim3(256),
                             args, 0, stream);
  hipLaunchKernelGGL(attn, dim3(1024), dim3(256), 0, stream,
                     tqs, w2t, q, kbf, vtb, attn_mask, mflags, gates, attn_output, out);
}

// Round 8
// 106.514 us; speedup vs baseline: 2.8142x; 2.8142x over previous
//
#include <hip/hip_runtime.h>
#include <hip/hip_bf16.h>

// ---------------- problem constants ----------------
#define B_    4
#define TQ_   1024
#define TKV_  1024
#define NPR_  5
#define H_    16
#define D_    64
#define IN_   1024
#define OUT_  1024
#define R_    64
#define KV_   1029            // NPR + TKV
#define KVP_  1088            // KV padded to 17*64
#define M1_   4116            // B*KV
#define M1P_  4160            // padded to 65*64
#define MQ_   4096            // B*TQ
#define NKT_  17              // KVP_/64
#define NQT_  16
#define MR_   (M1P_ * R_)     // 266240, one partial-chunk slice
#define LOG2E_ 1.4426950408889634f
#define SQ_SCALE_ (0.125f * 1.4426950408889634f)

typedef __attribute__((ext_vector_type(8))) short short8;
typedef __attribute__((ext_vector_type(4))) float f32x4;
typedef __attribute__((ext_vector_type(4))) unsigned uint4v;
typedef __attribute__((ext_vector_type(2))) unsigned uint2v;

#define MFMA(a, b, c) __builtin_amdgcn_mfma_f32_16x16x32_bf16(a, b, c, 0, 0, 0)

#define AS1 __attribute__((address_space(1)))
#define AS3 __attribute__((address_space(3)))
#define GLDS(g, l) __builtin_amdgcn_global_load_lds((const AS1 void*)(g), (AS3 void*)(l), 16, 0, 0)

static __device__ __forceinline__ short f2bf(float f) {
  unsigned u = __builtin_bit_cast(unsigned, f);
  u += 0x7fffu + ((u >> 16) & 1u);
  return (short)(u >> 16);
}
static __device__ __forceinline__ float bf2f(unsigned short u) {
  return __builtin_bit_cast(float, (unsigned)u << 16);
}
static __device__ __forceinline__ short8 zero8() {
  short8 z = {0, 0, 0, 0, 0, 0, 0, 0};
  return z;
}
static __device__ __forceinline__ unsigned cvtpk(float lo, float hi) {
  unsigned r;
  asm("v_cvt_pk_bf16_f32 %0, %1, %2" : "=v"(r) : "v"(lo), "v"(hi));
  return r;
}
static __device__ __forceinline__ float vexp2(float x) {   // raw v_exp (2^x)
  float r;
  asm("v_exp_f32 %0, %1" : "=v"(r) : "v"(x));
  return r;
}
static __device__ __forceinline__ void pl32(unsigned &a, unsigned &b) {
  asm("v_permlane32_swap_b32 %0, %1" : "+v"(a), "+v"(b));
}
static __device__ __forceinline__ void pl16(unsigned &a, unsigned &b) {
  asm("v_permlane16_swap_b32 %0, %1" : "+v"(a), "+v"(b));
}
static __device__ __forceinline__ float redsum4(float x) {
  unsigned a = __builtin_bit_cast(unsigned, x), b = a;
  pl16(a, b);
  x = __builtin_bit_cast(float, a) + __builtin_bit_cast(float, b);
  a = b = __builtin_bit_cast(unsigned, x);
  pl32(a, b);
  return __builtin_bit_cast(float, a) + __builtin_bit_cast(float, b);
}
// C-layout f32 s[4] -> bf16 B-fragments (validated R1..R7)
static __device__ __forceinline__ void cd2bfrag(const f32x4 (&s)[4], short8 &p0, short8 &p1) {
  unsigned u00 = cvtpk(s[0][0], s[0][1]), u01 = cvtpk(s[0][2], s[0][3]);
  unsigned u10 = cvtpk(s[1][0], s[1][1]), u11 = cvtpk(s[1][2], s[1][3]);
  unsigned u20 = cvtpk(s[2][0], s[2][1]), u21 = cvtpk(s[2][2], s[2][3]);
  unsigned u30 = cvtpk(s[3][0], s[3][1]), u31 = cvtpk(s[3][2], s[3][3]);
  pl32(u00, u10); pl32(u01, u11); pl32(u20, u30); pl32(u21, u31);
  pl16(u00, u10); pl16(u01, u11); pl16(u20, u30); pl16(u21, u31);
  uint4v w0 = {u00, u01, u10, u11};
  uint4v w1 = {u20, u21, u30, u31};
  p0 = __builtin_bit_cast(short8, w0);
  p1 = __builtin_bit_cast(short8, w1);
}
// sum 4 bf16 partial chunks (stride MR_) -> bf16 fragment
static __device__ __forceinline__ short8 sum4pack(const unsigned short* p) {
  f32x4 lo = {0, 0, 0, 0}, hi = {0, 0, 0, 0};
#pragma unroll
  for (int c = 0; c < 4; ++c) {
    short8 v = *(const short8*)(p + (size_t)c * MR_);
#pragma unroll
    for (int j = 0; j < 4; ++j) {
      lo[j] += bf2f((unsigned short)v[j]);
      hi[j] += bf2f((unsigned short)v[j + 4]);
    }
  }
  uint4v u = {cvtpk(lo[0], lo[1]), cvtpk(lo[2], lo[3]),
              cvtpk(hi[0], hi[1]), cvtpk(hi[2], hi[3])};
  return __builtin_bit_cast(short8, u);
}

// ---------------- kernel 1: weights transpose + mask tile scan + pe->bf16 ----------------
__global__ __launch_bounds__(256) void prep(
    const float* __restrict__ kw1, const float* __restrict__ vw1,
    const float* __restrict__ kpw1, const float* __restrict__ qpw1,
    const float* __restrict__ kw2, const float* __restrict__ vw2,
    const float* __restrict__ kpw2, const float* __restrict__ qpw2,
    const float* __restrict__ mask, const float* __restrict__ pe,
    short* __restrict__ w1t, short* __restrict__ w2t,
    short* __restrict__ pebf, int* __restrict__ mflags) {
  int bid = blockIdx.x;
  if (bid < 64) {
    int tid = bid * 256 + threadIdx.x;
    const float* w1s[4] = {kw1, vw1, kpw1, qpw1};
    const float* w2s[4] = {kw2, vw2, kpw2, qpw2};
    for (int i = tid; i < 4 * R_ * IN_; i += 64 * 256) {
      int m = i >> 16, p = i & 65535, r = p >> 10, k = p & 1023;
      w1t[i] = f2bf(w1s[m][k * R_ + r]);
    }
    for (int i = tid; i < 4 * OUT_ * R_; i += 64 * 256) {
      int m = i >> 16, p = i & 65535, o = p >> 6, r = p & 63;
      w2t[i] = f2bf(w2s[m][r * OUT_ + o]);
    }
  } else if (bid < 336) {
    int t = bid - 64;                 // 0..271 : tile (qt, kt)
    int qt = t / NKT_, kt = t % NKT_;
    int nz = 0;
    for (int it = 0; it < 16; ++it) {
      int e = it * 256 + threadIdx.x;
      int rr = e >> 6, cc = e & 63;
      int kv = kt * 64 + cc;
      if (kv < KV_) {
        float v = mask[(size_t)(qt * 64 + rr) * KV_ + kv];
        nz |= (v != 0.0f);
      }
    }
    __shared__ int snz[4];
    unsigned long long bv = __ballot(nz);
    if ((threadIdx.x & 63) == 0) snz[threadIdx.x >> 6] = (bv != 0ULL);
    __syncthreads();
    if (threadIdx.x == 0) mflags[t] = snz[0] | snz[1] | snz[2] | snz[3];
  } else {                            // pe -> bf16 (4096x1024)
    int pb = bid - 336;               // 0..255
#pragma unroll
    for (int it = 0; it < 8; ++it) {
      int i = pb * 16384 + it * 2048 + threadIdx.x * 8;
      f32x4 a0 = *(const f32x4*)(pe + i);
      f32x4 a1 = *(const f32x4*)(pe + i + 4);
      uint4v u = {cvtpk(a0[0], a0[1]), cvtpk(a0[2], a0[3]),
                  cvtpk(a1[0], a1[1]), cvtpk(a1[2], a1[3])};
      *(uint4v*)(pebf + i) = u;
    }
  }
}

// ---------------- kernel 2: stage1, K-split x4, operand-swapped (C^T), packed stores ----------------
__global__ __launch_bounds__(256) void stage1(
    const float* __restrict__ prompt, const float* __restrict__ kv_query,
    const short* __restrict__ pebf, const int* __restrict__ indices_a,
    const int* __restrict__ indices_b, const int* __restrict__ task_idx,
    const short* __restrict__ w1t, unsigned short* __restrict__ part) {
  int which = blockIdx.z;
  int chunk = blockIdx.y;
  int mbase = blockIdx.x * 64;
  int lane = threadIdx.x & 63, wave = threadIdx.x >> 6;
  int lrow = lane & 15, lg = lane >> 4;
  int row = mbase + wave * 16 + lrow;

  const float* asrc_f = nullptr;      // which==0 path (f32)
  const short* asrc_b = nullptr;      // which==1/2 path (bf16 pe)
  if (which == 0) {
    int r = min(row, M1_ - 1);
    int b = r / KV_, t = r - b * KV_;
    asrc_f = (t < NPR_) ? prompt + (size_t)(task_idx[b] * NPR_ + t) * IN_
                        : kv_query + (size_t)(b * TKV_ + t - NPR_) * IN_;
  } else if (which == 1) {
    int r = min(row, M1_ - 1);
    int b = r / KV_, t = r - b * KV_;
    if (t >= NPR_) asrc_b = pebf + (size_t)indices_b[b * TKV_ + t - NPR_] * OUT_;
  } else {
    int r = min(row, MQ_ - 1);
    asrc_b = pebf + (size_t)indices_a[r] * OUT_;
  }
  const short* bt0 = w1t + (size_t)((which == 0) ? 0 : (which == 1) ? 2 : 3) * (R_ * IN_);
  const short* bt1 = w1t + (size_t)1 * (R_ * IN_);
  int k0base = chunk * 256;

  const f32x4 fz = {0, 0, 0, 0};
  f32x4 acc0[4], acc1[4];
#pragma unroll
  for (int f = 0; f < 4; ++f) { acc0[f] = fz; acc1[f] = fz; }

#pragma unroll
  for (int ks = 0; ks < 8; ++ks) {
    int kc = k0base + ks * 32 + lg * 8;
    short8 bdat;                      // data fragment = B operand
    if (which == 0) {
      f32x4 a0 = *(const f32x4*)(asrc_f + kc);
      f32x4 a1 = *(const f32x4*)(asrc_f + kc + 4);
      uint4v au = {cvtpk(a0[0], a0[1]), cvtpk(a0[2], a0[3]),
                   cvtpk(a1[0], a1[1]), cvtpk(a1[2], a1[3])};
      bdat = __builtin_bit_cast(short8, au);
    } else {
      bdat = asrc_b ? *(const short8*)(asrc_b + kc) : zero8();
    }
#pragma unroll
    for (int f = 0; f < 4; ++f) {
      short8 w0 = *(const short8*)(bt0 + (size_t)(f * 16 + lrow) * IN_ + kc);
      acc0[f] = MFMA(w0, bdat, acc0[f]);      // C^T: lane holds m=lrow, r runs
      if (which == 0) {
        short8 w1f = *(const short8*)(bt1 + (size_t)(f * 16 + lrow) * IN_ + kc);
        acc1[f] = MFMA(w1f, bdat, acc1[f]);
      }
    }
  }
  int o0 = (which == 0) ? 0 : (which == 1) ? 2 : 3;
  size_t mrow = (size_t)(mbase + wave * 16 + lrow) * R_;
  unsigned short* p0 = part + (size_t)(o0 * 4 + chunk) * MR_ + mrow;
#pragma unroll
  for (int f = 0; f < 4; ++f) {
    uint2v w = {cvtpk(acc0[f][0], acc0[f][1]), cvtpk(acc0[f][2], acc0[f][3])};
    *(uint2v*)(p0 + f * 16 + lg * 4) = w;
  }
  if (which == 0) {
    unsigned short* p1 = part + (size_t)(4 + chunk) * MR_ + mrow;
#pragma unroll
    for (int f = 0; f < 4; ++f) {
      uint2v w = {cvtpk(acc1[f][0], acc1[f][1]), cvtpk(acc1[f][2], acc1[f][3])};
      *(uint2v*)(p1 + f * 16 + lg * 4) = w;
    }
  }
}

// ---------------- kernel 3: stage2, fused 4-chunk reduce + proj -> swizzled tiles ----------------
// L<272: K-proj; L<544: V-proj; else tq partial-sum. XCD-affinity remap inside.
__global__ __launch_bounds__(256) void stage2(
    const unsigned short* __restrict__ part, const short* __restrict__ w2t,
    short* __restrict__ kbf, short* __restrict__ vtb, short* __restrict__ tqs) {
  int L = blockIdx.x;
  int lane = threadIdx.x & 63, wave = threadIdx.x >> 6;
  int lrow = lane & 15, lg = lane >> 4;
  const f32x4 fz = {0, 0, 0, 0};

  if (L < 272) {                       // ---- K: kbf = tk@k_w2 + tkp@kp_w2 ----
    int virt = (L & 7) * 34 + (L >> 3);      // nh-siblings share an XCD
    int mt = virt >> 2, nh = virt & 3;
    int orow = mt * 64 + wave * 16 + lrow;
    int ob = orow / KVP_, okv = orow - ob * KVP_;
    bool valid = (okv < KV_);
    int kt = okv >> 6, rin = okv & 63;
    int prow = ob * KV_ + min(okv, KV_ - 1);
    short8 b1[2], b2[2];
#pragma unroll
    for (int ks = 0; ks < 2; ++ks) {
      int kc = ks * 32 + lg * 8;
      b1[ks] = valid ? sum4pack(part + (size_t)prow * R_ + kc) : zero8();
      b2[ks] = valid ? sum4pack(part + (size_t)8 * MR_ + (size_t)prow * R_ + kc) : zero8();
    }
    const short* w2k  = w2t;
    const short* w2kp = w2t + (size_t)2 * (OUT_ * R_);
    int sw = (rin & 7) << 3;
#pragma unroll
    for (int i = 0; i < 4; ++i) {
      int nbase = (nh * 4 + i) * 64;
      int h = nbase >> 6;
      f32x4 acc[4];
#pragma unroll
      for (int f = 0; f < 4; ++f) acc[f] = fz;
#pragma unroll
      for (int ks = 0; ks < 2; ++ks) {
        int kc = ks * 32 + lg * 8;
#pragma unroll
        for (int f = 0; f < 4; ++f) {
          short8 aK  = *(const short8*)(w2k  + (size_t)(nbase + f * 16 + lrow) * R_ + kc);
          short8 aKP = *(const short8*)(w2kp + (size_t)(nbase + f * 16 + lrow) * R_ + kc);
          acc[f] = MFMA(aK,  b1[ks], acc[f]);
          acc[f] = MFMA(aKP, b2[ks], acc[f]);
        }
      }
      size_t tb = ((size_t)((ob * H_ + h) * NKT_ + kt) << 12);
#pragma unroll
      for (int f = 0; f < 4; ++f) {
        float v0 = valid ? acc[f][0] : 0.f, v1 = valid ? acc[f][1] : 0.f;
        float v2 = valid ? acc[f][2] : 0.f, v3 = valid ? acc[f][3] : 0.f;
        uint2v w = {cvtpk(v0, v1), cvtpk(v2, v3)};
        int d0 = f * 16 + lg * 4;
        *(uint2v*)(kbf + tb + rin * 64 + (d0 ^ sw)) = w;
      }
    }
  } else if (L < 544) {                // ---- V: vtb = (tv @ v_w2)^T ----
    int Lm = L - 272;
    int virt = (Lm & 7) * 34 + (Lm >> 3);
    int cb = virt >> 2, oh = virt & 3;
    short8 afr[8];
#pragma unroll
    for (int f = 0; f < 4; ++f)
#pragma unroll
      for (int ks = 0; ks < 2; ++ks) {
        int crow = cb * 64 + f * 16 + lrow;
        int bb = crow / KVP_, kvr = crow - bb * KVP_;
        afr[f * 2 + ks] = (kvr < KV_)
            ? sum4pack(part + (size_t)4 * MR_ + (size_t)(bb * KV_ + kvr) * R_ + ks * 32 + lg * 8)
            : zero8();
      }
    int bb = (cb * 64) / KVP_;
    int kvbase = cb * 64 - bb * KVP_;        // 64-aligned
    int kt = kvbase >> 6;
    const short* w2v = w2t + (size_t)1 * (OUT_ * R_);
#pragma unroll
    for (int i = 0; i < 4; ++i) {
      int obase = (oh * 4 + i) * 64;
      int o = obase + wave * 16 + lrow;
      int h = o >> 6, d = o & 63;
      f32x4 acc[4];
#pragma unroll
      for (int f = 0; f < 4; ++f) acc[f] = fz;
#pragma unroll
      for (int ks = 0; ks < 2; ++ks) {
        short8 bw = *(const short8*)(w2v + (size_t)o * R_ + ks * 32 + lg * 8);
#pragma unroll
        for (int f = 0; f < 4; ++f) acc[f] = MFMA(afr[f * 2 + ks], bw, acc[f]);
      }
      int sw = (d & 7) << 3;
      size_t tb = ((size_t)((bb * H_ + h) * NKT_ + kt) << 12);
#pragma unroll
      for (int f = 0; f < 4; ++f) {
        int kvin0 = f * 16 + lg * 4;
        float v0 = (kvbase + kvin0 + 0 < KV_) ? acc[f][0] : 0.f;
        float v1 = (kvbase + kvin0 + 1 < KV_) ? acc[f][1] : 0.f;
        float v2 = (kvbase + kvin0 + 2 < KV_) ? acc[f][2] : 0.f;
        float v3 = (kvbase + kvin0 + 3 < KV_) ? acc[f][3] : 0.f;
        uint2v w = {cvtpk(v0, v1), cvtpk(v2, v3)};
        *(uint2v*)(vtb + tb + d * 64 + (kvin0 ^ sw)) = w;
      }
    }
  } else {                             // ---- tq partial sum -> tqs ----
    int j = L - 544;                   // 0..15
#pragma unroll
    for (int it = 0; it < 8; ++it) {
      int idx = j * 16384 + it * 2048 + threadIdx.x * 8;
      short8 v = sum4pack(part + (size_t)12 * MR_ + idx);
      *(short8*)(tqs + idx) = v;
    }
  }
}

// ================= kernel 4: flash attention, 3-buffer 1-barrier pipeline =================
__global__ __launch_bounds__(256, 3) void attn(
    const short* __restrict__ tqs, const short* __restrict__ w2t,
    const float* __restrict__ qin,
    const short* __restrict__ kbf, const short* __restrict__ vtb,
    const float* __restrict__ mask, const int* __restrict__ mflags,
    const float* __restrict__ gates, const float* __restrict__ attn_in,
    float* __restrict__ out) {
  int bid = blockIdx.x;
  int xcd = bid & 7, wg = bid >> 3;
  int qt = wg & 15, g = wg >> 4;
  int grp = xcd * 8 + g;                 // all 16 qt of a (b,h) share one XCD
  int h = grp & 15, b = grp >> 4;

  int lane = threadIdx.x & 63, wave = threadIdx.x >> 6;
  int lrow = lane & 15, lg = lane >> 4;
  int qbase = qt * 64 + wave * 16;

  __shared__ __align__(16) short kvls[3][2][4096];   // [buf][K/V][64x64 swizzled]

  const short* ktile = kbf + ((size_t)grp * NKT_ << 12);
  const short* vtile = vtb + ((size_t)grp * NKT_ << 12);
  const short* kg = ktile + wave * 512 + lane * 8;
  const short* vg = vtile + wave * 512 + lane * 8;

  int sw = (lrow & 7) << 3;
  int offA = (lg * 8) ^ sw;
  int offB = (32 + lg * 8) ^ sw;
  const short* p0A = &kvls[0][0][lrow * 64 + offA];
  const short* p0B = &kvls[0][0][lrow * 64 + offB];
  const short* p1A = &kvls[1][0][lrow * 64 + offA];
  const short* p1B = &kvls[1][0][lrow * 64 + offB];
  const short* p2A = &kvls[2][0][lrow * 64 + offA];
  const short* p2B = &kvls[2][0][lrow * 64 + offB];
  const int* mfp = mflags + qt * NKT_;

  auto stage = [&](int t, int bsel) {
    const short* ks = kg + ((size_t)t << 12);
    const short* vs = vg + ((size_t)t << 12);
    GLDS(ks,        &kvls[bsel][0][wave * 512]);
    GLDS(ks + 2048, &kvls[bsel][0][wave * 512 + 2048]);
    GLDS(vs,        &kvls[bsel][1][wave * 512]);
    GLDS(vs + 2048, &kvls[bsel][1][wave * 512 + 2048]);
  };

  stage(0, 0);
  stage(1, 1);

  // mask-tile flag bitmask (wave-uniform -> scalar branches in the loop)
  int fl = 0;
#pragma unroll
  for (int t = 0; t < NKT_; ++t) fl |= (mfp[t] ? 1 : 0) << t;
  fl = __builtin_amdgcn_readfirstlane(fl);

  const f32x4 fz = {0, 0, 0, 0};
  short8 qa0, qa1;
  {
    const short* w2q = w2t + (size_t)3 * (OUT_ * R_);
    f32x4 qs[4];
#pragma unroll
    for (int f = 0; f < 4; ++f) qs[f] = fz;
#pragma unroll
    for (int ks = 0; ks < 2; ++ks) {
      short8 tqf = *(const short8*)(tqs + (size_t)(b * TQ_ + qbase + lrow) * R_ + ks * 32 + lg * 8);
#pragma unroll
      for (int f = 0; f < 4; ++f) {
        short8 wf = *(const short8*)(w2q + (size_t)(h * 64 + f * 16 + lrow) * R_ + ks * 32 + lg * 8);
        qs[f] = MFMA(wf, tqf, qs[f]);
      }
    }
    const float* qrow = qin + (size_t)(b * TQ_ + qbase + lrow) * OUT_ + h * 64;
#pragma unroll
    for (int f = 0; f < 4; ++f) {
      f32x4 qv = *(const f32x4*)(qrow + f * 16 + lg * 4);
#pragma unroll
      for (int r = 0; r < 4; ++r) qs[f][r] = (qs[f][r] + qv[r]) * SQ_SCALE_;
    }
    cd2bfrag(qs, qa0, qa1);
  }

  f32x4 oacc[4];
#pragma unroll
  for (int f = 0; f < 4; ++f) oacc[f] = fz;
  float plsum = 0.f;

  // mode: 0 = stage(t+2), 1 = no stage, 2 = last (vmcnt(0) + pad)
  auto tile = [&](int t, const short* pA, const short* pB, int sb, int mode) {
    if (mode == 2) asm volatile("s_waitcnt vmcnt(0)" ::: "memory");
    else           asm volatile("s_waitcnt vmcnt(4)" ::: "memory");   // tile t landed; t+1 in flight
    __builtin_amdgcn_sched_barrier(0);
    __builtin_amdgcn_s_barrier();     // all waves: t staged, and done reading buf[(t+2)%3]
    __builtin_amdgcn_sched_barrier(0);
    if (mode == 0) stage(t + 2, sb);

    f32x4 s[4];
#pragma unroll
    for (int f = 0; f < 4; ++f) {
      short8 kA = *(const short8*)(pA + f * 1024);
      short8 kB = *(const short8*)(pB + f * 1024);
      s[f] = MFMA(kA, qa0, fz);
      s[f] = MFMA(kB, qa1, s[f]);
    }
    short8 vfr[8];
#pragma unroll
    for (int f = 0; f < 4; ++f) {
      vfr[f * 2 + 0] = *(const short8*)(pA + 4096 + f * 1024);
      vfr[f * 2 + 1] = *(const short8*)(pB + 4096 + f * 1024);
    }
    if ((fl >> t) & 1) {                               // nonzero mask tile (rare)
      int kvb = t * 64;
      const float* mrp = mask + (size_t)(qbase + lrow) * KV_;
#pragma unroll
      for (int f = 0; f < 4; ++f)
#pragma unroll
        for (int r = 0; r < 4; ++r) {
          int kv = kvb + f * 16 + lg * 4 + r;
          if (kv < KV_) s[f][r] += mrp[kv] * LOG2E_;
        }
    }
    if (mode == 2) {                                   // pad kv >= KV_
#pragma unroll
      for (int f = 0; f < 4; ++f)
#pragma unroll
        for (int r = 0; r < 4; ++r) {
          int kv = t * 64 + f * 16 + lg * 4 + r;
          if (kv >= KV_) s[f][r] = -1e30f;
        }
    }
    // static softmax numerator: P = 2^S (S in log2 units, bounded by data)
#pragma unroll
    for (int f = 0; f < 4; ++f)
#pragma unroll
      for (int r = 0; r < 4; ++r) s[f][r] = vexp2(s[f][r]);
    f32x4 st = (s[0] + s[1]) + (s[2] + s[3]);
    plsum += (st[0] + st[1]) + (st[2] + st[3]);        // per-lane partial
    short8 pb0, pb1;
    cd2bfrag(s, pb0, pb1);
#pragma unroll
    for (int f = 0; f < 4; ++f) {
      oacc[f] = MFMA(vfr[f * 2 + 0], pb0, oacc[f]);
      oacc[f] = MFMA(vfr[f * 2 + 1], pb1, oacc[f]);
    }
  };

#pragma unroll 1
  for (int i = 0; i < 5; ++i) {                        // t = 0..14
    tile(3 * i + 0, p0A, p0B, 2, 0);
    tile(3 * i + 1, p1A, p1B, 0, 0);
    tile(3 * i + 2, p2A, p2B, 1, 0);
  }
  tile(15, p0A, p0B, 2, 1);
  tile(16, p1A, p1B, 0, 2);

  float lsum = redsum4(plsum);
  float sc = gates[0] / lsum;
  const float* ain = attn_in + (size_t)(b * TQ_ + qbase + lrow) * OUT_ + h * 64;
  float* op = out + (size_t)(b * TQ_ + qbase + lrow) * OUT_ + h * 64;
#pragma unroll
  for (int f = 0; f < 4; ++f) {
    f32x4 av = *(const f32x4*)(ain + f * 16 + lg * 4);
    f32x4 ov;
#pragma unroll
    for (int r = 0; r < 4; ++r) ov[r] = oacc[f][r] * sc + av[r];
    *(f32x4*)(op + f * 16 + lg * 4) = ov;
  }
}

// ---------------- launcher ----------------
extern "C" void kernel_launch(void* const* d_in, const int* in_sizes, int n_in,
                              void* d_out, int out_size, void* d_ws, size_t ws_size,
                              hipStream_t stream) {
  const float* pe          = (const float*)d_in[0];
  const float* attn_output = (const float*)d_in[1];
  const float* q           = (const float*)d_in[2];
  const float* kv_query    = (const float*)d_in[3];
  const float* attn_mask   = (const float*)d_in[4];
  const float* prompt      = (const float*)d_in[5];
  const float* gates       = (const float*)d_in[6];
  const float* k_w1        = (const float*)d_in[7];
  const float* k_w2        = (const float*)d_in[8];
  const float* v_w1        = (const float*)d_in[9];
  const float* v_w2        = (const float*)d_in[10];
  const float* kp_w1       = (const float*)d_in[11];
  const float* kp_w2       = (const float*)d_in[12];
  const float* qp_w1       = (const float*)d_in[13];
  const float* qp_w2       = (const float*)d_in[14];
  const int* indices_a     = (const int*)d_in[15];
  const int* indices_b     = (const int*)d_in[16];
  const int* task_idx      = (const int*)d_in[17];
  float* out = (float*)d_out;

  const size_t TILEB = (size_t)64 * NKT_ * 4096;      // elems per K or V buffer

  short* ws   = (short*)d_ws;
  short* w1t  = ws;                                   // 262144
  short* w2t  = w1t + 4 * 65536;                      // 262144
  unsigned short* part = (unsigned short*)(w2t + 4 * 65536);  // 16 * MR_
  short* tqs  = (short*)(part + (size_t)16 * MR_);    // 262144
  int* mflags = (int*)(tqs + (size_t)MQ_ * R_);       // 272 ints (pad to 1024 shorts)
  short* pebf = (short*)mflags + 1024;                // 4,194,304 (dead after stage1)
  short* kbf  = pebf;                                 // overlays pebf (stage2 onward)
  short* vtb  = kbf + TILEB;                          // fresh
  // total ≈ 28.4 MB

  hipLaunchKernelGGL(prep, dim3(592), dim3(256), 0, stream,
                     k_w1, v_w1, kp_w1, qp_w1, k_w2, v_w2, kp_w2, qp_w2,
                     attn_mask, pe, w1t, w2t, pebf, mflags);
  hipLaunchKernelGGL(stage1, dim3(65, 4, 3), dim3(256), 0, stream,
                     prompt, kv_query, pebf, indices_a, indices_b, task_idx, w1t, part);
  hipLaunchKernelGGL(stage2, dim3(560), dim3(256), 0, stream,
                     part, w2t, kbf, vtb, tqs);
  hipLaunchKernelGGL(attn, dim3(1024), dim3(256), 0, stream,
                     tqs, w2t, q, kbf, vtb, attn_mask, mflags, gates, attn_output, out);
}